// Round 4
// baseline (294.278 us; speedup 1.0000x reference)
//
#include <hip/hip_runtime.h>
#include <math.h>

// ---- problem constants ----
#define BB    2
#define TT    16
#define TP    17          // T_ = T+1
#define HH_   24
#define WW_   24
#define HWW   576         // HH*WW
#define DD    128
#define NHH   4
#define MLPD_ 512
#define NPIX  18432       // B*T*HW
#define NTOK  19584       // B*T_*HW
#define SCALE 0.17677669529663688f   // 1/sqrt(32)
#define OUT0_SIZE 2506752            // B*T_*HW*D

typedef unsigned short u16;
typedef __bf16 bf16x8 __attribute__((ext_vector_type(8)));
typedef float f32x4 __attribute__((ext_vector_type(4)));

__device__ __forceinline__ u16 f2b(float f) {
  unsigned u = __float_as_uint(f);
  u += 0x7FFFu + ((u >> 16) & 1u);
  return (u16)(u >> 16);
}
__device__ __forceinline__ float blo(unsigned u) { return __uint_as_float(u << 16); }
__device__ __forceinline__ float bhi(unsigned u) { return __uint_as_float(u & 0xFFFF0000u); }

__device__ __forceinline__ float dot8(uint4 u, const float* q) {
  float a = blo(u.x) * q[0] + bhi(u.x) * q[1];
  a += blo(u.y) * q[2] + bhi(u.y) * q[3];
  a += blo(u.z) * q[4] + bhi(u.z) * q[5];
  a += blo(u.w) * q[6] + bhi(u.w) * q[7];
  return a;
}
__device__ __forceinline__ void acc8(uint4 u, float pj, float* o) {
  o[0] += pj * blo(u.x); o[1] += pj * bhi(u.x);
  o[2] += pj * blo(u.y); o[3] += pj * bhi(u.y);
  o[4] += pj * blo(u.z); o[5] += pj * bhi(u.z);
  o[6] += pj * blo(u.w); o[7] += pj * bhi(u.w);
}

__device__ __forceinline__ float wsum64(float v) {
#pragma unroll
  for (int o = 32; o > 0; o >>= 1) v += __shfl_xor(v, o, 64);
  return v;
}

// ---- pack all weights to bf16, transposed to [N][K] ----  grid(1024) block(256)
__global__ void k_packw(const float* w0, const float* w1, const float* w2, const float* w3,
                        const float* w4, const float* w5, const float* w6, const float* w7,
                        const float* w8, const float* w9, u16* __restrict__ out) {
  int idx = blockIdx.x * 256 + threadIdx.x;   // 0..262143
  const float* src; int K, N, local;
  if (idx < 131072) {
    int seg = idx >> 14; local = idx & 16383; K = 128; N = 128;
    const float* tbl[8] = {w0, w1, w2, w3, w4, w5, w6, w7};
    src = tbl[seg];
  } else if (idx < 196608) { src = w8; local = idx - 131072; K = 128; N = 512; }
  else                     { src = w9; local = idx - 196608; K = 512; N = 128; }
  int nn = local / K, kk = local - (local / K) * K;
  out[idx] = f2b(src[(size_t)kk * N + nn]);
}

// ---- pack QKV biases ---- grid(1) block(384)
__global__ void k_packb(const float* sbq, const float* sbk, const float* sbv,
                        const float* tbq, const float* tbk, const float* tbv,
                        float* __restrict__ sb3, float* __restrict__ tb3) {
  int i = threadIdx.x;
  sb3[i] = i < 128 ? sbq[i] : (i < 256 ? sbk[i - 128] : sbv[i - 256]);
  tb3[i] = i < 128 ? tbq[i] : (i < 256 ? tbk[i - 128] : tbv[i - 256]);
}

// ---- CLS mean + LN ----  grid(2) block(128)
__global__ void k_cls(const float* __restrict__ q, const float* __restrict__ w,
                      const float* __restrict__ bb, float* __restrict__ cls_ln) {
  int b = blockIdx.x, d = threadIdx.x;
  const float* base = q + (size_t)b * TP * HWW * DD + d;   // frame 0
  float s = 0.f;
  for (int hw = 0; hw < HWW; ++hw) s += base[(size_t)hw * DD];
  float x = s * (1.0f / HWW);
  __shared__ float sm[DD];
  sm[d] = x;
  __syncthreads();
  float mean = 0.f;
  for (int i = 0; i < DD; i++) mean += sm[i];
  mean *= (1.0f / DD);
  float var = 0.f;
  for (int i = 0; i < DD; i++) { float t = sm[i] - mean; var += t * t; }
  var *= (1.0f / DD);
  cls_ln[b * DD + d] = (x - mean) * rsqrtf(var + 1e-5f) * w[d] + bb[d];
}

// ---- K/V projection of CLS rows (r<B) and zero-pad row (r==B, LN(0)=ln_b) ---- grid(3) block(128)
__global__ void k_clsproj(const float* __restrict__ cls_ln, const float* __restrict__ ln_b,
                          const float* __restrict__ Wk, const float* __restrict__ bk,
                          const float* __restrict__ Wv, const float* __restrict__ bv,
                          float* __restrict__ KC, float* __restrict__ VC,
                          u16* __restrict__ KCb, u16* __restrict__ VCb) {
  int r = blockIdx.x, d = threadIdx.x;
  __shared__ float xr[DD];
  xr[d] = (r < BB) ? cls_ln[r * DD + d] : ln_b[d];
  __syncthreads();
  float sk = bk[d], sv = bv[d];
  for (int e = 0; e < DD; e++) {
    float xe = xr[e];
    sk += xe * Wk[e * DD + d];
    sv += xe * Wv[e * DD + d];
  }
  KC[r * DD + d] = sk;
  VC[r * DD + d] = sv;
  KCb[r * DD + d] = f2b(sk);
  VCb[r * DD + d] = f2b(sv);
}

// ---- LayerNorm rows -> bf16. mode 0: identity rows; mode 1: visual rows of query ----
// grid(nrows/4) block(256)
__global__ void k_ln(const float* __restrict__ src, u16* __restrict__ dst,
                     const float* __restrict__ w, const float* __restrict__ bb,
                     int nrows, int mode) {
  int wid = (blockIdx.x * blockDim.x + threadIdx.x) >> 6;
  int lane = threadIdx.x & 63;
  if (wid >= nrows) return;
  size_t srow = wid;
  if (mode == 1) { int b2 = wid / (TT * HWW); int r = wid - b2 * (TT * HWW); srow = (size_t)b2 * TP * HWW + HWW + r; }
  const float* sp = src + srow * DD;
  float x0 = sp[lane], x1 = sp[lane + 64];
  float mean = wsum64(x0 + x1) * (1.0f / DD);
  float d0 = x0 - mean, d1 = x1 - mean;
  float var = wsum64(d0 * d0 + d1 * d1) * (1.0f / DD);
  float inv = rsqrtf(var + 1e-5f);
  u16* dp = dst + (size_t)wid * DD;
  dp[lane]      = f2b(d0 * inv * w[lane] + bb[lane]);
  dp[lane + 64] = f2b(d1 * inv * w[lane + 64] + bb[lane + 64]);
}

// ---- MFMA bf16 GEMM: C[orow, col0+c] = A[M x K]bf16 @ Wt[N x K]bf16^T + bias ----
// BM=BN=128, BK=64, 256 threads (4 waves, 2x2 quadrants of 64x64).
// outmode 1: orow = b*T_*HW + HW + (r % (T*HW)); epilogue: optional exact GELU, resid (fp32, ld=ldc).
__global__ __launch_bounds__(256) void k_gemm_mfma(
    const u16* __restrict__ A, int K,
    const u16* __restrict__ Wt, const float* __restrict__ bias,
    float* __restrict__ Cf, u16* __restrict__ Cb, int ldc,
    const float* __restrict__ resid, int outmode, int gelu) {
  __shared__ __align__(16) u16 As[128][72];
  __shared__ __align__(16) u16 Bs[128][72];
  int tx = threadIdx.x;
  int row0 = blockIdx.x * 128, col0 = blockIdx.y * 128;
  int lane = tx & 63, wid = tx >> 6;
  int wr = (wid >> 1) * 64, wc = (wid & 1) * 64;
  f32x4 z = {0.f, 0.f, 0.f, 0.f};
  f32x4 acc[4][4];
#pragma unroll
  for (int i = 0; i < 4; i++)
#pragma unroll
    for (int j = 0; j < 4; j++) acc[i][j] = z;

  for (int k0 = 0; k0 < K; k0 += 64) {
    if (k0) __syncthreads();
#pragma unroll
    for (int i = 0; i < 4; i++) {
      int c = tx + 256 * i;              // 0..1023 chunks of 8 bf16
      int r = c >> 3, c8 = (c & 7) * 8;
      *(uint4*)&As[r][c8] = *(const uint4*)&A [(size_t)(row0 + r) * K + k0 + c8];
      *(uint4*)&Bs[r][c8] = *(const uint4*)&Wt[(size_t)(col0 + r) * K + k0 + c8];
    }
    __syncthreads();
#pragma unroll
    for (int kk = 0; kk < 2; kk++) {
      int ko = kk * 32 + (lane >> 4) * 8;
      bf16x8 af[4], bfr[4];
#pragma unroll
      for (int f = 0; f < 4; f++) {
        af[f]  = *(const bf16x8*)&As[wr + f * 16 + (lane & 15)][ko];
        bfr[f] = *(const bf16x8*)&Bs[wc + f * 16 + (lane & 15)][ko];
      }
#pragma unroll
      for (int i = 0; i < 4; i++)
#pragma unroll
        for (int j = 0; j < 4; j++)
          acc[i][j] = __builtin_amdgcn_mfma_f32_16x16x32_bf16(af[i], bfr[j], acc[i][j], 0, 0, 0);
    }
  }

  int rbase = row0 + wr + (lane >> 4) * 4;
  int cbase = col0 + wc + (lane & 15);
#pragma unroll
  for (int i = 0; i < 4; i++) {
#pragma unroll
    for (int e = 0; e < 4; e++) {
      int r = rbase + i * 16 + e;
      size_t orow = r;
      if (outmode == 1) { int b2 = r / (TT * HWW); int rr = r - b2 * (TT * HWW); orow = (size_t)b2 * TP * HWW + HWW + rr; }
#pragma unroll
      for (int j = 0; j < 4; j++) {
        int c = cbase + j * 16;
        float v = acc[i][j][e] + bias[c];
        if (gelu) v = 0.5f * v * (1.0f + erff(v * 0.70710678118654752f));
        size_t oidx = orow * (size_t)ldc + c;
        if (resid) v += resid[oidx];
        if (Cf) Cf[oidx] = v; else Cb[oidx] = f2b(v);
      }
    }
  }
}

// ---- spatial local-window attention, tiled ---- grid(288) block(256)
// Block = 8x8 pixel tile of one frame; LDS holds the 12x12 halo K,V (bf16, XOR-swizzled).
// Thread = one (pixel, head): q in regs, 26 scores lane-local, serial in-reg softmax, PV lane-local.
// FAITHFUL MASK BUG: kv col j (j<25) masked by kernel-pos-j validity (col0=CLS!, col j=neigh j-1);
// col 25 (neigh 24) never masked. Invalid neighbors use pad row = proj(LN(0)).
__global__ __launch_bounds__(256) void k_sattn_tile(const u16* __restrict__ qkvb,
                                                    const u16* __restrict__ KCb,
                                                    const u16* __restrict__ VCb,
                                                    u16* __restrict__ outb) {
  __shared__ __align__(16) u16 Kt[144 * 128];
  __shared__ __align__(16) u16 Vt[144 * 128];
  int tid = threadIdx.x;
  int blk = blockIdx.x;             // f*9 + ty*3 + tx
  int f = blk / 9, t9 = blk - f * 9;
  int ty0 = (t9 / 3) * 8 - 2, tx0 = (t9 - (t9 / 3) * 3) * 8 - 2;
  size_t FB = (size_t)f * HWW * 384;

  // ---- stage halo K/V (144 rows x 128 bf16 each), swizzled ----
  for (int c = tid; c < 2304; c += 256) {
    int rr = c >> 4, c16 = c & 15;
    int yy = ty0 + rr / 12, xx = tx0 + (rr - (rr / 12) * 12);
    const u16 *ks, *vs;
    if (((unsigned)yy < 24u) & ((unsigned)xx < 24u)) {
      size_t base = FB + (size_t)(yy * 24 + xx) * 384;
      ks = qkvb + base + 128; vs = qkvb + base + 256;
    } else { ks = KCb + 256; vs = VCb + 256; }     // pad row (index 2)
    uint4 k4 = *(const uint4*)(ks + c16 * 8);
    uint4 v4 = *(const uint4*)(vs + c16 * 8);
    int dst = (rr * 256 + c16 * 16) ^ ((rr & 7) << 4);
    *(uint4*)((char*)Kt + dst) = k4;
    *(uint4*)((char*)Vt + dst) = v4;
  }
  __syncthreads();

  int p = tid >> 2, h = tid & 3;
  int py = p >> 3, px = p & 7;
  int y = ty0 + 2 + py, x = tx0 + 2 + px;       // pixel coords (in frame)
  int n = f * HWW + y * 24 + x;

  float q[32];
  {
    const uint4* qp = (const uint4*)(qkvb + (size_t)n * 384 + h * 32);
#pragma unroll
    for (int i = 0; i < 4; i++) {
      uint4 u = qp[i];
      q[i * 8 + 0] = blo(u.x); q[i * 8 + 1] = bhi(u.x);
      q[i * 8 + 2] = blo(u.y); q[i * 8 + 3] = bhi(u.y);
      q[i * 8 + 4] = blo(u.z); q[i * 8 + 5] = bhi(u.z);
      q[i * 8 + 6] = blo(u.w); q[i * 8 + 7] = bhi(u.w);
    }
  }

  float s[26];
  {   // CLS key (kv col 0); cls batch = n%2 = x&1
    const uint4* kp = (const uint4*)(KCb + (x & 1) * 128 + h * 32);
    float a = 0.f;
#pragma unroll
    for (int i = 0; i < 4; i++) a += dot8(kp[i], &q[i * 8]);
    s[0] = a;
  }
#pragma unroll
  for (int k = 0; k < 25; k++) {
    int lr = (py + k / 5) * 12 + px + (k - (k / 5) * 5);
    int rb = lr * 256 + h * 64, sw = (lr & 7) << 4;
    float a = 0.f;
#pragma unroll
    for (int i = 0; i < 4; i++) {
      uint4 u = *(const uint4*)((const char*)Kt + ((rb + i * 16) ^ sw));
      a += dot8(u, &q[i * 8]);
    }
    s[k + 1] = a;
  }

  float mx = -1e30f;
#pragma unroll
  for (int j = 0; j < 26; j++) {
    bool masked = false;
    if (j < 25) { int ym = y + j / 5 - 2, xm = x + (j - (j / 5) * 5) - 2;
                  masked = !(((unsigned)ym < 24u) & ((unsigned)xm < 24u)); }
    s[j] = masked ? -1e9f : s[j] * SCALE;
    mx = fmaxf(mx, s[j]);
  }
  float ssum = 0.f;
#pragma unroll
  for (int j = 0; j < 26; j++) { s[j] = __expf(s[j] - mx); ssum += s[j]; }
  float inv = 1.0f / ssum;

  float o[32];
#pragma unroll
  for (int d = 0; d < 32; d++) o[d] = 0.f;
  {   // CLS value
    const uint4* vp = (const uint4*)(VCb + (x & 1) * 128 + h * 32);
#pragma unroll
    for (int i = 0; i < 4; i++) acc8(vp[i], s[0], &o[i * 8]);
  }
#pragma unroll
  for (int k = 0; k < 25; k++) {
    int lr = (py + k / 5) * 12 + px + (k - (k / 5) * 5);
    int rb = lr * 256 + h * 64, sw = (lr & 7) << 4;
    float pj = s[k + 1];
#pragma unroll
    for (int i = 0; i < 4; i++) {
      uint4 u = *(const uint4*)((const char*)Vt + ((rb + i * 16) ^ sw));
      acc8(u, pj, &o[i * 8]);
    }
  }

  uint4 ov[4];
  unsigned* op = (unsigned*)ov;
#pragma unroll
  for (int i = 0; i < 16; i++)
    op[i] = (unsigned)f2b(o[2 * i] * inv) | ((unsigned)f2b(o[2 * i + 1] * inv) << 16);
  uint4* dst = (uint4*)(outb + (size_t)n * 128 + h * 32);
#pragma unroll
  for (int i = 0; i < 4; i++) dst[i] = ov[i];
}

// ---- copy CLS frame (frame 0) of query into xbuf ---- grid(576) block(256)
__global__ void k_copycls(const float* __restrict__ q, float* __restrict__ xb) {
  int idx = blockIdx.x * 256 + threadIdx.x;
  if (idx >= BB * HWW * DD) return;
  int b = idx / (HWW * DD);
  int r = idx - b * (HWW * DD);
  xb[(size_t)b * TP * HWW * DD + r] = q[(size_t)b * TP * HWW * DD + r];
}

// ---- temporal attention, lane-local dots ---- grid(576) block(256)
__global__ __launch_bounds__(256) void k_tattn(const float* __restrict__ qkv,
                                               u16* __restrict__ outb,
                                               float* __restrict__ logits) {
  __shared__ float Qs[8][TP][32];
  __shared__ float Ps[8][TP][17];
  int tid = threadIdx.x;
  int g = tid >> 5, lj = tid & 31;
  int s = blockIdx.x * 2 + (g >> 2);
  int h = g & 3;
  int b = s / HWW, hw = s - b * HWW;
  size_t base = ((size_t)b * TP * HWW + hw) * 384 + h * 32;
  const size_t TSTR = (size_t)HWW * 384;

  float kreg[32];
  {
    const float* kp = qkv + base + (size_t)(lj < 17 ? lj : 16) * TSTR + 128;
#pragma unroll
    for (int d4 = 0; d4 < 8; d4++) {
      float4 k4 = *(const float4*)(kp + d4 * 4);
      kreg[d4 * 4 + 0] = k4.x; kreg[d4 * 4 + 1] = k4.y;
      kreg[d4 * 4 + 2] = k4.z; kreg[d4 * 4 + 3] = k4.w;
    }
  }
  float vreg[TP];
#pragma unroll
  for (int t = 0; t < TP; t++) {
    Qs[g][t][lj] = qkv[base + (size_t)t * TSTR + lj];
    vreg[t]      = qkv[base + (size_t)t * TSTR + 256 + lj];
  }

  float* lp = logits + (size_t)s * (NHH * TP * TP) + (size_t)h * (TP * TP);
#pragma unroll 4
  for (int tq = 0; tq < TP; tq++) {
    const float4* qrow = (const float4*)&Qs[g][tq][0];
    float a0 = 0.f, a1 = 0.f, a2 = 0.f, a3 = 0.f;
#pragma unroll
    for (int d4 = 0; d4 < 8; d4++) {
      float4 q4 = qrow[d4];
      a0 += q4.x * kreg[d4 * 4 + 0];
      a1 += q4.y * kreg[d4 * 4 + 1];
      a2 += q4.z * kreg[d4 * 4 + 2];
      a3 += q4.w * kreg[d4 * 4 + 3];
    }
    float sc = ((a0 + a1) + (a2 + a3)) * SCALE;
    if (lj < 17) lp[tq * 17 + lj] = sc;       // logits (mask all-False)
    float scm = (lj < 17) ? sc : -1e30f;
    float mx = scm;
#pragma unroll
    for (int o = 16; o > 0; o >>= 1) mx = fmaxf(mx, __shfl_xor(mx, o, 32));
    float p = __expf(scm - mx);
    float sum = p;
#pragma unroll
    for (int o = 16; o > 0; o >>= 1) sum += __shfl_xor(sum, o, 32);
    if (lj < 17) Ps[g][tq][lj] = p * (1.0f / sum);
  }
#pragma unroll 4
  for (int tq = 0; tq < TP; tq++) {
    const float* prow = &Ps[g][tq][0];
    float o = 0.f;
#pragma unroll
    for (int t = 0; t < TP; t++) o += prow[t] * vreg[t];
    size_t r = ((size_t)b * TP + tq) * HWW + hw;
    outb[r * DD + h * 32 + lj] = f2b(o);
  }
}

// ---- average CLS frame over HW, broadcast back ---- grid(2) block(128)
__global__ void k_clsavg(float* __restrict__ x2) {
  int b = blockIdx.x, d = threadIdx.x;
  float* base = x2 + (size_t)b * TP * HWW * DD;
  float s = 0.f;
  for (int hw = 0; hw < HWW; ++hw) s += base[(size_t)hw * DD + d];
  float m = s * (1.0f / HWW);
  for (int hw = 0; hw < HWW; ++hw) base[(size_t)hw * DD + d] = m;
}

extern "C" void kernel_launch(void* const* d_in, const int* in_sizes, int n_in,
                              void* d_out, int out_size, void* d_ws, size_t ws_size,
                              hipStream_t stream) {
  const float* query  = (const float*)d_in[0];
  const float* ln_s_w = (const float*)d_in[3];
  const float* ln_s_b = (const float*)d_in[4];
  const float* sWq = (const float*)d_in[5];  const float* sbq = (const float*)d_in[6];
  const float* sWk = (const float*)d_in[7];  const float* sbk = (const float*)d_in[8];
  const float* sWv = (const float*)d_in[9];  const float* sbv = (const float*)d_in[10];
  const float* sWo = (const float*)d_in[11]; const float* sbo = (const float*)d_in[12];
  const float* ln_t_w = (const float*)d_in[13];
  const float* ln_t_b = (const float*)d_in[14];
  const float* tWq = (const float*)d_in[15]; const float* tbq = (const float*)d_in[16];
  const float* tWk = (const float*)d_in[17]; const float* tbk = (const float*)d_in[18];
  const float* tWv = (const float*)d_in[19]; const float* tbv = (const float*)d_in[20];
  const float* tWo = (const float*)d_in[21]; const float* tbo = (const float*)d_in[22];
  const float* ln_m_w = (const float*)d_in[23];
  const float* ln_m_b = (const float*)d_in[24];
  const float* mW1 = (const float*)d_in[25]; const float* mb1 = (const float*)d_in[26];
  const float* mW2 = (const float*)d_in[27]; const float* mb2 = (const float*)d_in[28];

  float* ws = (float*)d_ws;
  float* QKV = ws;                                   // f32, NTOK*384 (temporal)
  u16*   QKVb = (u16*)ws;                            // bf16, NPIX*384 (spatial; dead before QKV written)
  u16*   S0b = (u16*)(ws + 7520256);                 // bf16, NTOK*128
  float* XB  = ws + 8773632;                         // f32, NTOK*128
  float* X2  = ws + 11280384;                        // f32, NTOK*128
  u16*   WT  = (u16*)(ws + 13787136);                // bf16 packed weights (262,144)
  float* sb3 = ws + 13918208;                        // 384
  float* tb3 = ws + 13918592;                        // 384
  float* cls_ln = ws + 13918976;                     // 256
  float* KCp = ws + 13919232;                        // 384
  float* VCp = ws + 13919616;                        // 384
  u16*   KCb = (u16*)(ws + 13920000);                // 384 bf16
  u16*   VCb = (u16*)(ws + 13920192);                // 384 bf16
  u16*   H1b = (u16*)ws;                             // bf16 NTOK*512, aliases QKV (dead by then)

  float* out0   = (float*)d_out;
  float* logits = out0 + OUT0_SIZE;

  // ---- packing ----
  k_packw<<<1024, 256, 0, stream>>>(sWq, sWk, sWv, sWo, tWq, tWk, tWv, tWo, mW1, mW2, WT);
  k_packb<<<1, 384, 0, stream>>>(sbq, sbk, sbv, tbq, tbk, tbv, sb3, tb3);

  // ---- spatial branch ----
  k_cls<<<2, 128, 0, stream>>>(query, ln_s_w, ln_s_b, cls_ln);
  k_clsproj<<<3, 128, 0, stream>>>(cls_ln, ln_s_b, sWk, sbk, sWv, sbv, KCp, VCp, KCb, VCb);
  k_ln<<<NPIX / 4, 256, 0, stream>>>(query, S0b, ln_s_w, ln_s_b, NPIX, 1);
  k_gemm_mfma<<<dim3(NPIX / 128, 3), 256, 0, stream>>>(S0b, 128, WT, sb3, nullptr, QKVb, 384, nullptr, 0, 0);
  k_sattn_tile<<<288, 256, 0, stream>>>(QKVb, KCb, VCb, S0b);
  k_gemm_mfma<<<dim3(NPIX / 128, 1), 256, 0, stream>>>(S0b, 128, WT + 49152, sbo, XB, nullptr, 128, query, 1, 0);
  k_copycls<<<(BB * HWW * DD + 255) / 256, 256, 0, stream>>>(query, XB);

  // ---- temporal branch ----
  k_ln<<<NTOK / 4, 256, 0, stream>>>(XB, S0b, ln_t_w, ln_t_b, NTOK, 0);
  k_gemm_mfma<<<dim3(NTOK / 128, 3), 256, 0, stream>>>(S0b, 128, WT + 65536, tb3, QKV, nullptr, 384, nullptr, 0, 0);
  k_tattn<<<BB * HWW / 2, 256, 0, stream>>>(QKV, S0b, logits);
  k_gemm_mfma<<<dim3(NTOK / 128, 1), 256, 0, stream>>>(S0b, 128, WT + 114688, tbo, X2, nullptr, 128, XB, 0, 0);
  k_clsavg<<<2, 128, 0, stream>>>(X2);

  // ---- MLP ----
  k_ln<<<NTOK / 4, 256, 0, stream>>>(X2, S0b, ln_m_w, ln_m_b, NTOK, 0);
  k_gemm_mfma<<<dim3(NTOK / 128, 4), 256, 0, stream>>>(S0b, 128, WT + 131072, mb1, nullptr, H1b, 512, nullptr, 0, 1);
  k_gemm_mfma<<<dim3(NTOK / 128, 1), 256, 0, stream>>>(H1b, 512, WT + 196608, mb2, out0, nullptr, 128, X2, 0, 0);
}

// Round 5
// 218.966 us; speedup vs baseline: 1.3439x; 1.3439x over previous
//
#include <hip/hip_runtime.h>
#include <math.h>

// ---- problem constants ----
#define BB    2
#define TT    16
#define TP    17          // T_ = T+1
#define HH_   24
#define WW_   24
#define HWW   576         // HH*WW
#define DD    128
#define NHH   4
#define MLPD_ 512
#define NPIX  18432       // B*T*HW
#define NTOK  19584       // B*T_*HW
#define SCALE 0.17677669529663688f   // 1/sqrt(32)
#define OUT0_SIZE 2506752            // B*T_*HW*D

typedef unsigned short u16;
typedef __bf16 bf16x8 __attribute__((ext_vector_type(8)));
typedef float f32x4 __attribute__((ext_vector_type(4)));

__device__ __forceinline__ u16 f2b(float f) {
  unsigned u = __float_as_uint(f);
  u += 0x7FFFu + ((u >> 16) & 1u);
  return (u16)(u >> 16);
}
__device__ __forceinline__ float blo(unsigned u) { return __uint_as_float(u << 16); }
__device__ __forceinline__ float bhi(unsigned u) { return __uint_as_float(u & 0xFFFF0000u); }
__device__ __forceinline__ float b2f(u16 u) { return __uint_as_float((unsigned)u << 16); }

__device__ __forceinline__ float dot8p(uint4 a, uint4 b) {
  float s = blo(a.x) * blo(b.x) + bhi(a.x) * bhi(b.x);
  s += blo(a.y) * blo(b.y) + bhi(a.y) * bhi(b.y);
  s += blo(a.z) * blo(b.z) + bhi(a.z) * bhi(b.z);
  s += blo(a.w) * blo(b.w) + bhi(a.w) * bhi(b.w);
  return s;
}
// compile-time component select (j constant after unroll -> folds, no scratch)
__device__ __forceinline__ float getp(const float4* P, int j) {
  float4 v = P[j >> 2];
  switch (j & 3) { case 0: return v.x; case 1: return v.y; case 2: return v.z; default: return v.w; }
}

__device__ __forceinline__ float wsum64(float v) {
#pragma unroll
  for (int o = 32; o > 0; o >>= 1) v += __shfl_xor(v, o, 64);
  return v;
}

// ---- pack all weights to bf16, transposed to [N][K] ----  grid(1024) block(256)
__global__ void k_packw(const float* w0, const float* w1, const float* w2, const float* w3,
                        const float* w4, const float* w5, const float* w6, const float* w7,
                        const float* w8, const float* w9, u16* __restrict__ out) {
  int idx = blockIdx.x * 256 + threadIdx.x;   // 0..262143
  const float* src; int K, N, local;
  if (idx < 131072) {
    int seg = idx >> 14; local = idx & 16383; K = 128; N = 128;
    const float* tbl[8] = {w0, w1, w2, w3, w4, w5, w6, w7};
    src = tbl[seg];
  } else if (idx < 196608) { src = w8; local = idx - 131072; K = 128; N = 512; }
  else                     { src = w9; local = idx - 196608; K = 512; N = 128; }
  int nn = local / K, kk = local - (local / K) * K;
  out[idx] = f2b(src[(size_t)kk * N + nn]);
}

// ---- pack QKV biases ---- grid(1) block(384)
__global__ void k_packb(const float* sbq, const float* sbk, const float* sbv,
                        const float* tbq, const float* tbk, const float* tbv,
                        float* __restrict__ sb3, float* __restrict__ tb3) {
  int i = threadIdx.x;
  sb3[i] = i < 128 ? sbq[i] : (i < 256 ? sbk[i - 128] : sbv[i - 256]);
  tb3[i] = i < 128 ? tbq[i] : (i < 256 ? tbk[i - 128] : tbv[i - 256]);
}

// ---- CLS mean + LN ----  grid(2) block(1024)
__global__ void k_cls(const float* __restrict__ q, const float* __restrict__ w,
                      const float* __restrict__ bb, float* __restrict__ cls_ln) {
  __shared__ float part[8][DD];
  __shared__ float xsh[DD];
  int b = blockIdx.x, tid = threadIdx.x;
  int c = tid >> 7, d = tid & 127;
  const float* base = q + (size_t)b * TP * HWW * DD + d;   // frame 0
  float s = 0.f;
  for (int hw = c * 72; hw < c * 72 + 72; ++hw) s += base[(size_t)hw * DD];
  part[c][d] = s;
  __syncthreads();
  if (tid < DD) {
    float x = 0.f;
#pragma unroll
    for (int i = 0; i < 8; i++) x += part[i][tid];
    xsh[tid] = x * (1.0f / HWW);
  }
  __syncthreads();
  if (tid < DD) {
    float mean = 0.f;
    for (int i = 0; i < DD; i++) mean += xsh[i];
    mean *= (1.0f / DD);
    float var = 0.f;
    for (int i = 0; i < DD; i++) { float t = xsh[i] - mean; var += t * t; }
    var *= (1.0f / DD);
    cls_ln[b * DD + tid] = (xsh[tid] - mean) * rsqrtf(var + 1e-5f) * w[tid] + bb[tid];
  }
}

// ---- K/V projection of CLS rows (r<B) and zero-pad row (r==B, LN(0)=ln_b) ---- grid(3) block(512)
__global__ void k_clsproj(const float* __restrict__ cls_ln, const float* __restrict__ ln_b,
                          const float* __restrict__ Wk, const float* __restrict__ bk,
                          const float* __restrict__ Wv, const float* __restrict__ bv,
                          float* __restrict__ KC, float* __restrict__ VC,
                          u16* __restrict__ KCb, u16* __restrict__ VCb) {
  __shared__ float xr[DD];
  __shared__ float pk[4][DD], pv[4][DD];
  int r = blockIdx.x, tid = threadIdx.x;
  int c = tid >> 7, d = tid & 127;
  if (tid < DD) xr[tid] = (r < BB) ? cls_ln[r * DD + tid] : ln_b[tid];
  __syncthreads();
  float sk = 0.f, sv = 0.f;
  for (int e = c * 32; e < c * 32 + 32; e++) {
    float xe = xr[e];
    sk += xe * Wk[e * DD + d];
    sv += xe * Wv[e * DD + d];
  }
  pk[c][d] = sk; pv[c][d] = sv;
  __syncthreads();
  if (tid < DD) {
    float k = pk[0][tid] + pk[1][tid] + pk[2][tid] + pk[3][tid] + bk[tid];
    float v = pv[0][tid] + pv[1][tid] + pv[2][tid] + pv[3][tid] + bv[tid];
    KC[r * DD + tid] = k;  VC[r * DD + tid] = v;
    KCb[r * DD + tid] = f2b(k);  VCb[r * DD + tid] = f2b(v);
  }
}

// ---- LayerNorm rows -> bf16. mode 0: identity rows; mode 1: visual rows of query ----
// grid(nrows/4) block(256)
__global__ void k_ln(const float* __restrict__ src, u16* __restrict__ dst,
                     const float* __restrict__ w, const float* __restrict__ bb,
                     int nrows, int mode) {
  int wid = (blockIdx.x * blockDim.x + threadIdx.x) >> 6;
  int lane = threadIdx.x & 63;
  if (wid >= nrows) return;
  size_t srow = wid;
  if (mode == 1) { int b2 = wid / (TT * HWW); int r = wid - b2 * (TT * HWW); srow = (size_t)b2 * TP * HWW + HWW + r; }
  const float* sp = src + srow * DD;
  float x0 = sp[lane], x1 = sp[lane + 64];
  float mean = wsum64(x0 + x1) * (1.0f / DD);
  float d0 = x0 - mean, d1 = x1 - mean;
  float var = wsum64(d0 * d0 + d1 * d1) * (1.0f / DD);
  float inv = rsqrtf(var + 1e-5f);
  u16* dp = dst + (size_t)wid * DD;
  dp[lane]      = f2b(d0 * inv * w[lane] + bb[lane]);
  dp[lane + 64] = f2b(d1 * inv * w[lane + 64] + bb[lane + 64]);
}

// ---- MFMA bf16 GEMM: C[orow, col0+c] = A[M x K]bf16 @ Wt[N x K]bf16^T + bias ----
// BM=BN=128, BK=64, 256 threads (4 waves, 2x2 quadrants of 64x64).
// outmode 1: orow = b*T_*HW + HW + (r % (T*HW)); epilogue: optional exact GELU, resid (fp32, ld=ldc).
__global__ __launch_bounds__(256) void k_gemm_mfma(
    const u16* __restrict__ A, int K,
    const u16* __restrict__ Wt, const float* __restrict__ bias,
    float* __restrict__ Cf, u16* __restrict__ Cb, int ldc,
    const float* __restrict__ resid, int outmode, int gelu) {
  __shared__ __align__(16) u16 As[128][72];
  __shared__ __align__(16) u16 Bs[128][72];
  int tx = threadIdx.x;
  int row0 = blockIdx.x * 128, col0 = blockIdx.y * 128;
  int lane = tx & 63, wid = tx >> 6;
  int wr = (wid >> 1) * 64, wc = (wid & 1) * 64;
  f32x4 z = {0.f, 0.f, 0.f, 0.f};
  f32x4 acc[4][4];
#pragma unroll
  for (int i = 0; i < 4; i++)
#pragma unroll
    for (int j = 0; j < 4; j++) acc[i][j] = z;

  for (int k0 = 0; k0 < K; k0 += 64) {
    if (k0) __syncthreads();
#pragma unroll
    for (int i = 0; i < 4; i++) {
      int c = tx + 256 * i;              // 0..1023 chunks of 8 bf16
      int r = c >> 3, c8 = (c & 7) * 8;
      *(uint4*)&As[r][c8] = *(const uint4*)&A [(size_t)(row0 + r) * K + k0 + c8];
      *(uint4*)&Bs[r][c8] = *(const uint4*)&Wt[(size_t)(col0 + r) * K + k0 + c8];
    }
    __syncthreads();
#pragma unroll
    for (int kk = 0; kk < 2; kk++) {
      int ko = kk * 32 + (lane >> 4) * 8;
      bf16x8 af[4], bfr[4];
#pragma unroll
      for (int f = 0; f < 4; f++) {
        af[f]  = *(const bf16x8*)&As[wr + f * 16 + (lane & 15)][ko];
        bfr[f] = *(const bf16x8*)&Bs[wc + f * 16 + (lane & 15)][ko];
      }
#pragma unroll
      for (int i = 0; i < 4; i++)
#pragma unroll
        for (int j = 0; j < 4; j++)
          acc[i][j] = __builtin_amdgcn_mfma_f32_16x16x32_bf16(af[i], bfr[j], acc[i][j], 0, 0, 0);
    }
  }

  int rbase = row0 + wr + (lane >> 4) * 4;
  int cbase = col0 + wc + (lane & 15);
#pragma unroll
  for (int i = 0; i < 4; i++) {
#pragma unroll
    for (int e = 0; e < 4; e++) {
      int r = rbase + i * 16 + e;
      size_t orow = r;
      if (outmode == 1) { int b2 = r / (TT * HWW); int rr = r - b2 * (TT * HWW); orow = (size_t)b2 * TP * HWW + HWW + rr; }
#pragma unroll
      for (int j = 0; j < 4; j++) {
        int c = cbase + j * 16;
        float v = acc[i][j][e] + bias[c];
        if (gelu) v = 0.5f * v * (1.0f + erff(v * 0.70710678118654752f));
        size_t oidx = orow * (size_t)ldc + c;
        if (resid) v += resid[oidx];
        if (Cf) Cf[oidx] = v; else Cb[oidx] = f2b(v);
      }
    }
  }
}

// ---- spatial local-window attention: 32-lane group per (pixel, head) ---- grid(9216) block(256)
// Phase A: lane j = kv column j (j<26): lane-local bf16 dot, butterfly softmax (10 shuffles total).
// Phase B: lane d = output dim d: P via 7 ds_read_b128 broadcasts, 26 lane-local FMAs vs V from L2.
// FAITHFUL MASK BUG: kv col j (j<25) masked by kernel-pos-j validity (col0=CLS!, col j=neigh j-1);
// col 25 (neigh 24) never masked. Invalid neighbors use pad row = proj(LN(0)).
__global__ __launch_bounds__(256) void k_sattn(const u16* __restrict__ qkvb,
                                               const u16* __restrict__ KCb,
                                               const u16* __restrict__ VCb,
                                               u16* __restrict__ outb) {
  __shared__ float Ps[8][32];
  int tid = threadIdx.x;
  int g = tid >> 5, lj = tid & 31;
  int G = blockIdx.x * 8 + g;          // 0..73727
  int n = G >> 2, h = G & 3;
  int f = n / HWW, hw = n - f * HWW;
  int hp = hw / WW_, wp = hw - hp * WW_;
  size_t FB = (size_t)f * HWW * 384;

  // ---- phase A: score for kv col lj ----
  const u16* kp;
  bool masked;
  if (lj == 0) {
    kp = KCb + (n & 1) * DD + h * 32;          // CLS key, batch = n % B
    masked = !(hp >= 2 && wp >= 2);            // kernel-pos 0 validity
  } else {
    int k = lj - 1;                            // neighbor index (0..24 meaningful)
    int y = hp + k / 5 - 2, x = wp + k % 5 - 2;
    bool vok = ((unsigned)y < 24u) & ((unsigned)x < 24u) & (k < 25);
    kp = vok ? (qkvb + FB + (size_t)(y * WW_ + x) * 384 + 128 + h * 32)
             : (KCb + BB * DD + h * 32);       // pad row
    if (lj < 25) { int ym = hp + lj / 5 - 2, xm = wp + lj % 5 - 2;
                   masked = !(((unsigned)ym < 24u) & ((unsigned)xm < 24u)); }
    else masked = false;
  }
  const uint4* q4p = (const uint4*)(qkvb + (size_t)n * 384 + h * 32);
  const uint4* k4p = (const uint4*)kp;
  float s = 0.f;
#pragma unroll
  for (int i = 0; i < 4; i++) s += dot8p(q4p[i], k4p[i]);

  float scr = masked ? -1e9f : s * SCALE;
  if (lj >= 26) scr = -1e30f;
  float mx = scr;
#pragma unroll
  for (int o = 16; o > 0; o >>= 1) mx = fmaxf(mx, __shfl_xor(mx, o, 32));
  float p = __expf(scr - mx);
  float sum = p;
#pragma unroll
  for (int o = 16; o > 0; o >>= 1) sum += __shfl_xor(sum, o, 32);
  Ps[g][lj] = p * (1.0f / sum);                // lanes >=26 write 0

  // ---- phase B: output dim d = lj ----
  float4 P4[7];
#pragma unroll
  for (int i = 0; i < 7; i++) P4[i] = *(const float4*)&Ps[g][i * 4];

  float o = getp(P4, 0) * b2f(VCb[(n & 1) * DD + h * 32 + lj]);   // CLS value
#pragma unroll
  for (int k = 0; k < 25; k++) {               // kv col k+1 = neighbor k
    int y = hp + k / 5 - 2, x = wp + k % 5 - 2;
    bool vok = ((unsigned)y < 24u) & ((unsigned)x < 24u);
    const u16* vp = vok ? (qkvb + FB + (size_t)(y * WW_ + x) * 384 + 256)
                        : (VCb + BB * DD);
    o += getp(P4, k + 1) * b2f(vp[h * 32 + lj]);
  }
  outb[(size_t)n * DD + h * 32 + lj] = f2b(o);
}

// ---- copy CLS frame (frame 0) of query into xbuf ---- grid(576) block(256)
__global__ void k_copycls(const float* __restrict__ q, float* __restrict__ xb) {
  int idx = blockIdx.x * 256 + threadIdx.x;
  if (idx >= BB * HWW * DD) return;
  int b = idx / (HWW * DD);
  int r = idx - b * (HWW * DD);
  xb[(size_t)b * TP * HWW * DD + r] = q[(size_t)b * TP * HWW * DD + r];
}

// ---- temporal attention, lane-local dots ---- grid(576) block(256)
__global__ __launch_bounds__(256) void k_tattn(const float* __restrict__ qkv,
                                               u16* __restrict__ outb,
                                               float* __restrict__ logits) {
  __shared__ float Qs[8][TP][32];
  __shared__ float Ps[8][TP][17];
  int tid = threadIdx.x;
  int g = tid >> 5, lj = tid & 31;
  int s = blockIdx.x * 2 + (g >> 2);
  int h = g & 3;
  int b = s / HWW, hw = s - b * HWW;
  size_t base = ((size_t)b * TP * HWW + hw) * 384 + h * 32;
  const size_t TSTR = (size_t)HWW * 384;

  float kreg[32];
  {
    const float* kp = qkv + base + (size_t)(lj < 17 ? lj : 16) * TSTR + 128;
#pragma unroll
    for (int d4 = 0; d4 < 8; d4++) {
      float4 k4 = *(const float4*)(kp + d4 * 4);
      kreg[d4 * 4 + 0] = k4.x; kreg[d4 * 4 + 1] = k4.y;
      kreg[d4 * 4 + 2] = k4.z; kreg[d4 * 4 + 3] = k4.w;
    }
  }
  float vreg[TP];
#pragma unroll
  for (int t = 0; t < TP; t++) {
    Qs[g][t][lj] = qkv[base + (size_t)t * TSTR + lj];
    vreg[t]      = qkv[base + (size_t)t * TSTR + 256 + lj];
  }

  float* lp = logits + (size_t)s * (NHH * TP * TP) + (size_t)h * (TP * TP);
#pragma unroll 4
  for (int tq = 0; tq < TP; tq++) {
    const float4* qrow = (const float4*)&Qs[g][tq][0];
    float a0 = 0.f, a1 = 0.f, a2 = 0.f, a3 = 0.f;
#pragma unroll
    for (int d4 = 0; d4 < 8; d4++) {
      float4 q4 = qrow[d4];
      a0 += q4.x * kreg[d4 * 4 + 0];
      a1 += q4.y * kreg[d4 * 4 + 1];
      a2 += q4.z * kreg[d4 * 4 + 2];
      a3 += q4.w * kreg[d4 * 4 + 3];
    }
    float sc = ((a0 + a1) + (a2 + a3)) * SCALE;
    if (lj < 17) lp[tq * 17 + lj] = sc;       // logits (mask all-False)
    float scm = (lj < 17) ? sc : -1e30f;
    float mx = scm;
#pragma unroll
    for (int o = 16; o > 0; o >>= 1) mx = fmaxf(mx, __shfl_xor(mx, o, 32));
    float p = __expf(scm - mx);
    float sum = p;
#pragma unroll
    for (int o = 16; o > 0; o >>= 1) sum += __shfl_xor(sum, o, 32);
    if (lj < 17) Ps[g][tq][lj] = p * (1.0f / sum);
  }
#pragma unroll 4
  for (int tq = 0; tq < TP; tq++) {
    const float* prow = &Ps[g][tq][0];
    float o = 0.f;
#pragma unroll
    for (int t = 0; t < TP; t++) o += prow[t] * vreg[t];
    size_t r = ((size_t)b * TP + tq) * HWW + hw;
    outb[r * DD + h * 32 + lj] = f2b(o);
  }
}

// ---- average CLS frame over HW, broadcast back ---- grid(2) block(1024)
__global__ void k_clsavg(float* __restrict__ x2) {
  __shared__ float part[8][DD];
  __shared__ float m[DD];
  int b = blockIdx.x, tid = threadIdx.x;
  int c = tid >> 7, d = tid & 127;
  float* base = x2 + (size_t)b * TP * HWW * DD;
  float s = 0.f;
  for (int hw = c * 72; hw < c * 72 + 72; ++hw) s += base[(size_t)hw * DD + d];
  part[c][d] = s;
  __syncthreads();
  if (tid < DD) {
    float x = 0.f;
#pragma unroll
    for (int i = 0; i < 8; i++) x += part[i][tid];
    m[tid] = x * (1.0f / HWW);
  }
  __syncthreads();
  float mv = m[d];
  for (int hw = c * 72; hw < c * 72 + 72; ++hw) base[(size_t)hw * DD + d] = mv;
}

extern "C" void kernel_launch(void* const* d_in, const int* in_sizes, int n_in,
                              void* d_out, int out_size, void* d_ws, size_t ws_size,
                              hipStream_t stream) {
  const float* query  = (const float*)d_in[0];
  const float* ln_s_w = (const float*)d_in[3];
  const float* ln_s_b = (const float*)d_in[4];
  const float* sWq = (const float*)d_in[5];  const float* sbq = (const float*)d_in[6];
  const float* sWk = (const float*)d_in[7];  const float* sbk = (const float*)d_in[8];
  const float* sWv = (const float*)d_in[9];  const float* sbv = (const float*)d_in[10];
  const float* sWo = (const float*)d_in[11]; const float* sbo = (const float*)d_in[12];
  const float* ln_t_w = (const float*)d_in[13];
  const float* ln_t_b = (const float*)d_in[14];
  const float* tWq = (const float*)d_in[15]; const float* tbq = (const float*)d_in[16];
  const float* tWk = (const float*)d_in[17]; const float* tbk = (const float*)d_in[18];
  const float* tWv = (const float*)d_in[19]; const float* tbv = (const float*)d_in[20];
  const float* tWo = (const float*)d_in[21]; const float* tbo = (const float*)d_in[22];
  const float* ln_m_w = (const float*)d_in[23];
  const float* ln_m_b = (const float*)d_in[24];
  const float* mW1 = (const float*)d_in[25]; const float* mb1 = (const float*)d_in[26];
  const float* mW2 = (const float*)d_in[27]; const float* mb2 = (const float*)d_in[28];

  float* ws = (float*)d_ws;
  float* QKV = ws;                                   // f32, NTOK*384 (temporal)
  u16*   QKVb = (u16*)ws;                            // bf16, NPIX*384 (spatial; dead before QKV written)
  u16*   S0b = (u16*)(ws + 7520256);                 // bf16, NTOK*128
  float* XB  = ws + 8773632;                         // f32, NTOK*128
  float* X2  = ws + 11280384;                        // f32, NTOK*128
  u16*   WT  = (u16*)(ws + 13787136);                // bf16 packed weights (262,144)
  float* sb3 = ws + 13918208;                        // 384
  float* tb3 = ws + 13918592;                        // 384
  float* cls_ln = ws + 13918976;                     // 256
  float* KCp = ws + 13919232;                        // 384
  float* VCp = ws + 13919616;                        // 384
  u16*   KCb = (u16*)(ws + 13920000);                // 384 bf16
  u16*   VCb = (u16*)(ws + 13920192);                // 384 bf16
  u16*   H1b = (u16*)ws;                             // bf16 NTOK*512, aliases QKV (dead by then)

  float* out0   = (float*)d_out;
  float* logits = out0 + OUT0_SIZE;

  // ---- packing ----
  k_packw<<<1024, 256, 0, stream>>>(sWq, sWk, sWv, sWo, tWq, tWk, tWv, tWo, mW1, mW2, WT);
  k_packb<<<1, 384, 0, stream>>>(sbq, sbk, sbv, tbq, tbk, tbv, sb3, tb3);

  // ---- spatial branch ----
  k_cls<<<2, 1024, 0, stream>>>(query, ln_s_w, ln_s_b, cls_ln);
  k_clsproj<<<3, 512, 0, stream>>>(cls_ln, ln_s_b, sWk, sbk, sWv, sbv, KCp, VCp, KCb, VCb);
  k_ln<<<NPIX / 4, 256, 0, stream>>>(query, S0b, ln_s_w, ln_s_b, NPIX, 1);
  k_gemm_mfma<<<dim3(NPIX / 128, 3), 256, 0, stream>>>(S0b, 128, WT, sb3, nullptr, QKVb, 384, nullptr, 0, 0);
  k_sattn<<<NPIX * NHH / 8, 256, 0, stream>>>(QKVb, KCb, VCb, S0b);
  k_gemm_mfma<<<dim3(NPIX / 128, 1), 256, 0, stream>>>(S0b, 128, WT + 49152, sbo, XB, nullptr, 128, query, 1, 0);
  k_copycls<<<(BB * HWW * DD + 255) / 256, 256, 0, stream>>>(query, XB);

  // ---- temporal branch ----
  k_ln<<<NTOK / 4, 256, 0, stream>>>(XB, S0b, ln_t_w, ln_t_b, NTOK, 0);
  k_gemm_mfma<<<dim3(NTOK / 128, 3), 256, 0, stream>>>(S0b, 128, WT + 65536, tb3, QKV, nullptr, 384, nullptr, 0, 0);
  k_tattn<<<BB * HWW / 2, 256, 0, stream>>>(QKV, S0b, logits);
  k_gemm_mfma<<<dim3(NTOK / 128, 1), 256, 0, stream>>>(S0b, 128, WT + 114688, tbo, X2, nullptr, 128, XB, 0, 0);
  k_clsavg<<<2, 1024, 0, stream>>>(X2);

  // ---- MLP ----
  k_ln<<<NTOK / 4, 256, 0, stream>>>(X2, S0b, ln_m_w, ln_m_b, NTOK, 0);
  k_gemm_mfma<<<dim3(NTOK / 128, 4), 256, 0, stream>>>(S0b, 128, WT + 131072, mb1, nullptr, H1b, 512, nullptr, 0, 1);
  k_gemm_mfma<<<dim3(NTOK / 128, 1), 256, 0, stream>>>(H1b, 512, WT + 196608, mb2, out0, nullptr, 128, X2, 0, 0);
}